// Round 15
// baseline (239.485 us; speedup 1.0000x reference)
//
#include <hip/hip_runtime.h>
#include <hip/hip_bf16.h>
#include <stdint.h>

#define NNODES 100000
#define NEDGES 1000000
#define NRELS 16
#define EPB 2048
#define NB ((NEDGES + EPB - 1) / EPB)   /* 489 */
#define PADCAP (NEDGES + NRELS * 64)    /* 1001024 */
#define MAXTILES (PADCAP / 64)          /* 15641 */
#define NDN NNODES
#define BKT 256
#define NBKT ((NDN + BKT - 1) / BKT)     /* 391 */

#define FEAT_BLKS 6250
#define W_BLKS 256
#define SETUP_BLKS (FEAT_BLKS + W_BLKS + NB)
#define SCANS_BLKS (1 + (NBKT + 15) / 16)

// ws layout (bytes), all offsets 256-aligned (Round-3 proven layout):
//   featB   @ 0          : ushort[NNODES*64]     -> 12,800,000
//   Wt      @ 12800000   : ushort[16*64*64]      -> 12,931,072
//   hist16  @ 12931072   : int[NB*16]            -> 12,963,840
//   bbase16 @ 12963840   : int[NB*16]            -> 12,996,608
//   Pve     @ 12996608   : int[33]               -> 12,996,864
//   hist391 @ 12996864   : int[NB*NBKT]          -> 13,764,864
//   bbase391@ 13764864   : int[NB*NBKT]          -> 14,532,864
//   bstart  @ 14532864   : int[NBKT+1]           -> 14,534,912
//   dnstart @ 14534912   : int[NBKT*256+1]       -> 14,935,552
//   keyP    @ 14935552   : int[NEDGES]           -> 18,935,552
//   inv     @ 18935552   : int[PADCAP]           -> 22,939,648
//   srcS    @ 22939648   : int[PADCAP]           -> 26,943,744
//   msgE    @ 26943744   : ushort[PADCAP*64]     -> 155,074,816
#define OFF_FEATB    0ull
#define OFF_WT       12800000ull
#define OFF_HIST16   12931072ull
#define OFF_BBASE16  12963840ull
#define OFF_PVE      12996608ull
#define OFF_HIST391  12996864ull
#define OFF_BBASE391 13764864ull
#define OFF_BSTART   14532864ull
#define OFF_DNSTART  14534912ull
#define OFF_KEYP     14935552ull
#define OFF_INV      18935552ull
#define OFF_SRCS     22939648ull
#define OFF_MSGE     26943744ull
#define WS_NEED 155074816ull

using short8  = __attribute__((ext_vector_type(8))) short;
using floatx4 = __attribute__((ext_vector_type(4))) float;
using uintx2  = __attribute__((ext_vector_type(2))) unsigned int;
using uintx4  = __attribute__((ext_vector_type(4))) unsigned int;

__device__ __forceinline__ unsigned short f2bf(float f) {
    union { float f; uint32_t u; } v; v.f = f;
    uint32_t u = v.u;
    return (unsigned short)((u + 0x7FFFu + ((u >> 16) & 1u)) >> 16);
}
__device__ __forceinline__ float bf2f(uint32_t u16) {
    union { uint32_t u; float f; } v; v.u = u16 << 16;
    return v.f;
}
__device__ __forceinline__ uint32_t pk2(float a, float b) {
    __hip_bfloat162 h = __float22bfloat162_rn(make_float2(a, b));
    union { __hip_bfloat162 h; uint32_t u; } v; v.h = h;
    return v.u;
}

// fused setup: feat->bf16, W->bf16 transposed, per-block rel hist + dst-bucket hist.
__global__ void k_setup(const float* __restrict__ feat, const float* __restrict__ W,
                        const int* __restrict__ et, const int* __restrict__ dst,
                        unsigned short* __restrict__ featB, unsigned short* __restrict__ Wt,
                        int* __restrict__ hist16, int* __restrict__ hist391) {
    __shared__ int cnt16[16];
    __shared__ int cnt391[NBKT];
    const int b = blockIdx.x;
    if (b < FEAT_BLKS) {
        int i = (b * 256 + threadIdx.x) * 4;
        const float4 f = *(const float4*)(feat + i);
        ushort4 o;
        o.x = f2bf(f.x); o.y = f2bf(f.y); o.z = f2bf(f.z); o.w = f2bf(f.w);
        *(ushort4*)(featB + i) = o;
    } else if (b < FEAT_BLKS + W_BLKS) {
        int t = (b - FEAT_BLKS) * 256 + threadIdx.x;   // 65536 total
        int r = t >> 12, n = (t >> 6) & 63, k = t & 63;
        Wt[t] = f2bf(W[(r << 12) + (k << 6) + n]);     // Wt[r][n][k] = W[r][k][n]
    } else {
        const int bb = b - (FEAT_BLKS + W_BLKS);
        if (threadIdx.x < 16) cnt16[threadIdx.x] = 0;
        for (int t = threadIdx.x; t < NBKT; t += 256) cnt391[t] = 0;
        __syncthreads();
        int start = bb * EPB;
        int end = min(NEDGES, start + EPB);
        for (int i = start + threadIdx.x; i < end; i += 256) {
            atomicAdd(&cnt16[et[i]], 1);
            atomicAdd(&cnt391[dst[i] >> 8], 1);
        }
        __syncthreads();
        if (threadIdx.x < 16) hist16[bb * 16 + threadIdx.x] = cnt16[threadIdx.x];
        for (int t = threadIdx.x; t < NBKT; t += 256)
            hist391[bb * NBKT + t] = cnt391[t];
    }
}

// merged: block 0 = relation scan (16 waves, with 64-pad via Pve); blocks 1.. = bucket scanA
__global__ void __launch_bounds__(1024)
k_scans(const int* __restrict__ hist16, int* __restrict__ bbase16,
        int* __restrict__ Pve,
        const int* __restrict__ hist391, int* __restrict__ bbase391,
        int* __restrict__ bstart) {
    int w = threadIdx.x >> 6;
    int lane = threadIdx.x & 63;
    if (blockIdx.x == 0) {
        __shared__ int s_cnt[16];
        __shared__ int s_P[17];
        int carry = 0;
        for (int c = 0; c < NB; c += 64) {
            int idx = c + lane;
            int v = (idx < NB) ? hist16[idx * 16 + w] : 0;
            int x = v;
            #pragma unroll
            for (int off = 1; off < 64; off <<= 1) {
                int y = __shfl_up(x, off);
                if (lane >= off) x += y;
            }
            if (idx < NB) bbase16[idx * 16 + w] = carry + x - v;
            carry += __shfl(x, 63);
        }
        if (lane == 0) s_cnt[w] = carry;
        __syncthreads();
        if (threadIdx.x == 0) {
            int p = 0;
            for (int r = 0; r < 16; ++r) {
                s_P[r] = p;
                Pve[r] = p;
                Pve[17 + r] = p + s_cnt[r];
                p += (s_cnt[r] + 63) & ~63;
            }
            s_P[16] = p;
            Pve[16] = p;
        }
        __syncthreads();
        int pw = s_P[w];
        for (int idx = lane; idx < NB; idx += 64)
            bbase16[idx * 16 + w] += pw;
    } else {
        int b = (blockIdx.x - 1) * 16 + w;
        if (b >= NBKT) return;
        int carry = 0;
        for (int c = 0; c < NB; c += 64) {
            int idx = c + lane;
            int v = (idx < NB) ? hist391[idx * NBKT + b] : 0;
            int x = v;
            #pragma unroll
            for (int off = 1; off < 64; off <<= 1) {
                int y = __shfl_up(x, off);
                if (lane >= off) x += y;
            }
            if (idx < NB) bbase391[idx * NBKT + b] = carry + x - v;
            carry += __shfl(x, 63);
        }
        if (lane == 0) bstart[b] = carry;   // totals; scanned in k_bscanB
    }
}

// bucket scan B: parallel exclusive scan over NBKT totals (one block, 512 thr)
__global__ void k_bscanB(int* __restrict__ bstart) {
    __shared__ int wtot[8];
    int t = threadIdx.x;
    int v = (t < NBKT) ? bstart[t] : 0;
    int lane = t & 63, w = t >> 6;
    int x = v;
    #pragma unroll
    for (int off = 1; off < 64; off <<= 1) {
        int y = __shfl_up(x, off);
        if (lane >= off) x += y;
    }
    if (lane == 63) wtot[w] = x;
    __syncthreads();
    int woff = 0;
    for (int i = 0; i < w; ++i) woff += wtot[i];
    if (t < NBKT) bstart[t] = woff + x - v;
    if (t == 511) {
        int total = 0;
        for (int i = 0; i < 8; ++i) total += wtot[i];
        bstart[NBKT] = total;
    }
}

// scatter: srcS[relpos] = src; keyP[bp] = (relpos<<8)|(dst&255)  (packed, one store).
__global__ void k_scatter(const int* __restrict__ et, const int* __restrict__ src,
                          const int* __restrict__ dst, const int* __restrict__ bbase16,
                          const int* __restrict__ bbase391, const int* __restrict__ bstart,
                          int* __restrict__ srcS, int* __restrict__ keyP) {
    __shared__ int base16[16];
    __shared__ int base391[NBKT];
    if (threadIdx.x < 16) base16[threadIdx.x] = bbase16[blockIdx.x * 16 + threadIdx.x];
    for (int t = threadIdx.x; t < NBKT; t += 256)
        base391[t] = bbase391[blockIdx.x * NBKT + t] + bstart[t];
    __syncthreads();
    int start = blockIdx.x * EPB;
    int end = min(NEDGES, start + EPB);
    for (int i = start + threadIdx.x; i < end; i += 256) {
        int r = et[i];
        int pos = atomicAdd(&base16[r], 1);
        srcS[pos] = src[i];
        int d = dst[i];
        int bp = atomicAdd(&base391[d >> 8], 1);
        keyP[bp] = (pos << 8) | (d & 255);   // pos < 2^20, fits
    }
}

// refine bucket order into full dst sort; write INVERSE map: inv[relpos] = dstpos.
__global__ void __launch_bounds__(256)
k_bsort(const int* __restrict__ keyP, const int* __restrict__ bstart,
        int* __restrict__ inv, int* __restrict__ dnstart) {
    __shared__ int cnt[256];
    __shared__ int nodebase[256];
    __shared__ int wtot[4];
    const int b = blockIdx.x;
    const int start = bstart[b], end = bstart[b + 1];
    const int t = threadIdx.x;
    cnt[t] = 0;
    __syncthreads();
    for (int e = start + t; e < end; e += 256)
        atomicAdd(&cnt[keyP[e] & 255], 1);
    __syncthreads();
    int v = cnt[t];
    int lane = t & 63, w = t >> 6;
    int x = v;
    #pragma unroll
    for (int off = 1; off < 64; off <<= 1) {
        int y = __shfl_up(x, off);
        if (lane >= off) x += y;
    }
    if (lane == 63) wtot[w] = x;
    __syncthreads();
    int woff = 0;
    for (int i = 0; i < w; ++i) woff += wtot[i];
    nodebase[t] = woff + x - v;          // exclusive scan
    cnt[t] = 0;
    __syncthreads();
    dnstart[b * 256 + t] = start + nodebase[t];
    if (b == NBKT - 1 && t == 255) dnstart[NBKT * 256] = end;
    for (int e = start + t; e < end; e += 256) {
        int k = keyP[e];
        int node = k & 255;
        int rk = atomicAdd(&cnt[node], 1);
        inv[k >> 8] = start + nodebase[node] + rk;   // relpos -> dstpos
    }
}

// Phase A: per 64-edge tile (single relation), GEMM -> scatter to dst-sorted
// position (inv map).
//  - keep-alive asm pins all 16 A/W fragments in registers BEFORE compute:
//    the load cluster (~24 VMEM) stays in flight together (r11 showed
//    sched_barrier alone doesn't stop load sinking: VGPR stayed 52).
//  - SWAPPED-operand MFMA: mfma(W-frag, feat-frag) -> D[n][e]; C-layout
//    col=lane&15=edge, row=quad*4+j=channel -> each lane holds 4 CONSECUTIVE
//    channels of one edge per tn => direct 8-B packed stores, NO LDS at all.
__global__ void __launch_bounds__(256)
k_computeA(const unsigned short* __restrict__ featB,
           const unsigned short* __restrict__ Wt,
           const int* __restrict__ srcS, const int* __restrict__ Pve,
           const int* __restrict__ inv,
           unsigned short* __restrict__ msgE) {
    const int w = threadIdx.x >> 6;
    const int t = blockIdx.x * 4 + w;
    const int base = t * 64;
    const int lane = threadIdx.x & 63;

    // wave-parallel relation lookup (base is wave-uniform)
    int pv = (lane < 33) ? Pve[lane] : 0x7fffffff;
    int total = __shfl(pv, 16);
    if (base >= total) return;
    unsigned long long bm = __ballot(lane >= 1 && lane <= 16 && pv <= base);
    int r = __popcll(bm);                 // Pve[r] <= base < Pve[r+1]
    int validEnd = __shfl(pv, 17 + r);

    const int quad = lane >> 4;
    const int l16 = lane & 15;

    // --- load cluster: srcS + inv (both l16-indexed: lane's edge) ---
    int s[4]; int dpos[4]; bool vld[4];
    #pragma unroll
    for (int tm = 0; tm < 4; ++tm) {
        int row = base + tm * 16 + l16;
        vld[tm] = (row < validEnd);
        s[tm]    = vld[tm] ? srcS[row] : 0;
        dpos[tm] = vld[tm] ? inv[row] : 0;
    }
    // --- load cluster: W fragments (L2-hot) ---
    const unsigned short* wr = Wt + (r << 12);
    short8 bfr[4][2];
    #pragma unroll
    for (int tn = 0; tn < 4; ++tn)
        #pragma unroll
        for (int ks = 0; ks < 2; ++ks)
            bfr[tn][ks] = *(const short8*)(wr + ((tn * 16 + l16) << 6) + ks * 32 + quad * 8);
    // --- load cluster: all 8 feature gathers ---
    short8 a[4][2];
    #pragma unroll
    for (int tm = 0; tm < 4; ++tm) {
        const unsigned short* fp = featB + ((size_t)s[tm] << 6) + quad * 8;
        a[tm][0] = *(const short8*)(fp);
        a[tm][1] = *(const short8*)(fp + 32);
    }
    // hard use of every fragment: loads cannot sink past this point.
    // Expect VGPR ~100 (was 52) as the verification signature.
    asm volatile("" ::
        "v"(a[0][0]), "v"(a[0][1]), "v"(a[1][0]), "v"(a[1][1]),
        "v"(a[2][0]), "v"(a[2][1]), "v"(a[3][0]), "v"(a[3][1]),
        "v"(bfr[0][0]), "v"(bfr[0][1]), "v"(bfr[1][0]), "v"(bfr[1][1]),
        "v"(bfr[2][0]), "v"(bfr[2][1]), "v"(bfr[3][0]), "v"(bfr[3][1]));
    __builtin_amdgcn_sched_barrier(0);

    // --- compute (swapped operands) + direct packed stores ---
    #pragma unroll
    for (int tm = 0; tm < 4; ++tm) {
        unsigned short* op = msgE + (size_t)dpos[tm] * 64 + quad * 4;
        #pragma unroll
        for (int tn = 0; tn < 4; ++tn) {
            floatx4 c = {0.f, 0.f, 0.f, 0.f};
            c = __builtin_amdgcn_mfma_f32_16x16x32_bf16(bfr[tn][0], a[tm][0], c, 0, 0, 0);
            c = __builtin_amdgcn_mfma_f32_16x16x32_bf16(bfr[tn][1], a[tm][1], c, 0, 0, 0);
            // c[j] = msg[edge = base+tm*16+l16][channel = tn*16 + quad*4 + j]
            if (vld[tm]) {
                uintx2 o;
                o.x = pk2(c[0], c[1]);
                o.y = pk2(c[2], c[3]);
                *(uintx2*)(op + tn * 16) = o;
            }
        }
    }
}

// Phase B: one wave per dst node; rows CONTIGUOUS in msgE -> sequential reads.
__global__ void __launch_bounds__(256)
k_reduce(const unsigned short* __restrict__ msgE,
         const int* __restrict__ dnstart, float* __restrict__ out) {
    int n = blockIdx.x * 4 + (threadIdx.x >> 6);
    if (n >= NDN) return;
    int lane = threadIdx.x & 63;
    int start = dnstart[n];
    int end = dnstart[n + 1];
    int c8 = (lane & 7) * 8;   // ushort col offset
    float a0 = 0.f, a1 = 0.f, a2 = 0.f, a3 = 0.f;
    float a4 = 0.f, a5 = 0.f, a6 = 0.f, a7 = 0.f;
    int row = start + (lane >> 3);
    for (; row + 8 < end; row += 16) {
        uintx4 v0 = *(const uintx4*)(msgE + (size_t)row * 64 + c8);
        uintx4 v1 = *(const uintx4*)(msgE + (size_t)(row + 8) * 64 + c8);
        a0 += bf2f(v0.x & 0xffffu); a1 += bf2f(v0.x >> 16);
        a2 += bf2f(v0.y & 0xffffu); a3 += bf2f(v0.y >> 16);
        a4 += bf2f(v0.z & 0xffffu); a5 += bf2f(v0.z >> 16);
        a6 += bf2f(v0.w & 0xffffu); a7 += bf2f(v0.w >> 16);
        a0 += bf2f(v1.x & 0xffffu); a1 += bf2f(v1.x >> 16);
        a2 += bf2f(v1.y & 0xffffu); a3 += bf2f(v1.y >> 16);
        a4 += bf2f(v1.z & 0xffffu); a5 += bf2f(v1.z >> 16);
        a6 += bf2f(v1.w & 0xffffu); a7 += bf2f(v1.w >> 16);
    }
    if (row < end) {
        uintx4 v = *(const uintx4*)(msgE + (size_t)row * 64 + c8);
        a0 += bf2f(v.x & 0xffffu); a1 += bf2f(v.x >> 16);
        a2 += bf2f(v.y & 0xffffu); a3 += bf2f(v.y >> 16);
        a4 += bf2f(v.z & 0xffffu); a5 += bf2f(v.z >> 16);
        a6 += bf2f(v.w & 0xffffu); a7 += bf2f(v.w >> 16);
    }
    #pragma unroll
    for (int m = 8; m <= 32; m <<= 1) {
        a0 += __shfl_xor(a0, m); a1 += __shfl_xor(a1, m);
        a2 += __shfl_xor(a2, m); a3 += __shfl_xor(a3, m);
        a4 += __shfl_xor(a4, m); a5 += __shfl_xor(a5, m);
        a6 += __shfl_xor(a6, m); a7 += __shfl_xor(a7, m);
    }
    if (lane < 8) {
        float* op = out + (size_t)n * 64 + lane * 8;
        *(float4*)(op)     = make_float4(a0, a1, a2, a3);
        *(float4*)(op + 4) = make_float4(a4, a5, a6, a7);
    }
}

// Fallback (ws too small): correctness-only per-edge kernel on raw fp32 inputs.
__global__ void __launch_bounds__(256)
k_fb(const float* __restrict__ feat, const float* __restrict__ W,
     const int* __restrict__ src, const int* __restrict__ dst,
     const int* __restrict__ et, float* __restrict__ out) {
    int e = blockIdx.x * 4 + (threadIdx.x >> 6);
    if (e >= NEDGES) return;
    int c = threadIdx.x & 63;
    int s = src[e], d = dst[e], r = et[e];
    const float* fr = feat + (size_t)s * 64;
    const float* wr = W + ((size_t)r << 12);
    float acc = 0.f;
    for (int k = 0; k < 64; ++k) acc += fr[k] * wr[k * 64 + c];
    atomicAdd(out + (size_t)d * 64 + c, acc);
}

extern "C" void kernel_launch(void* const* d_in, const int* in_sizes, int n_in,
                              void* d_out, int out_size, void* d_ws, size_t ws_size,
                              hipStream_t stream) {
    const float* feat = (const float*)d_in[0];
    const float* W    = (const float*)d_in[1];
    const int* src    = (const int*)d_in[2];
    const int* dst    = (const int*)d_in[3];
    const int* et     = (const int*)d_in[4];
    float* out = (float*)d_out;
    char* ws = (char*)d_ws;

    unsigned short* featB = (unsigned short*)(ws + OFF_FEATB);
    unsigned short* Wt    = (unsigned short*)(ws + OFF_WT);
    int* hist16   = (int*)(ws + OFF_HIST16);
    int* bbase16  = (int*)(ws + OFF_BBASE16);
    int* Pve      = (int*)(ws + OFF_PVE);
    int* hist391  = (int*)(ws + OFF_HIST391);
    int* bbase391 = (int*)(ws + OFF_BBASE391);
    int* bstart   = (int*)(ws + OFF_BSTART);
    int* dnstart  = (int*)(ws + OFF_DNSTART);
    int* keyP     = (int*)(ws + OFF_KEYP);
    int* inv      = (int*)(ws + OFF_INV);
    int* srcS     = (int*)(ws + OFF_SRCS);
    unsigned short* msgE = (unsigned short*)(ws + OFF_MSGE);

    if (ws_size >= WS_NEED) {
        k_setup<<<SETUP_BLKS, 256, 0, stream>>>(feat, W, et, dst, featB, Wt,
                                                hist16, hist391);
        k_scans<<<SCANS_BLKS, 1024, 0, stream>>>(hist16, bbase16, Pve, hist391,
                                                 bbase391, bstart);
        k_bscanB<<<1, 512, 0, stream>>>(bstart);
        k_scatter<<<NB, 256, 0, stream>>>(et, src, dst, bbase16, bbase391, bstart,
                                          srcS, keyP);
        k_bsort<<<NBKT, 256, 0, stream>>>(keyP, bstart, inv, dnstart);
        k_computeA<<<(MAXTILES + 3) / 4, 256, 0, stream>>>(featB, Wt, srcS, Pve,
                                                           inv, msgE);
        k_reduce<<<(NDN + 3) / 4, 256, 0, stream>>>(msgE, dnstart, out);
    } else {
        hipMemsetAsync(d_out, 0, (size_t)out_size * sizeof(float), stream);
        k_fb<<<(NEDGES + 3) / 4, 256, 0, stream>>>(feat, W, src, dst, et, out);
    }
}

// Round 16
// 211.407 us; speedup vs baseline: 1.1328x; 1.1328x over previous
//
#include <hip/hip_runtime.h>
#include <hip/hip_bf16.h>
#include <stdint.h>

#define NNODES 100000
#define NEDGES 1000000
#define NRELS 16
#define EPB 2048
#define NB ((NEDGES + EPB - 1) / EPB)   /* 489 */
#define PADCAP (NEDGES + NRELS * 64)    /* 1001024 */
#define MAXTILES (PADCAP / 64)          /* 15641 */
#define NDN NNODES
#define BKT 256
#define NBKT ((NDN + BKT - 1) / BKT)     /* 391 */

#define FEAT_BLKS 6250
#define W_BLKS 256
#define SETUP_BLKS (FEAT_BLKS + W_BLKS + NB)
#define SCANS_BLKS (1 + (NBKT + 15) / 16)

// ws layout (bytes), all offsets 256-aligned (Round-3 proven layout):
//   featB   @ 0          : ushort[NNODES*64]     -> 12,800,000
//   Wt      @ 12800000   : ushort[16*64*64]      -> 12,931,072
//   hist16  @ 12931072   : int[NB*16]            -> 12,963,840
//   bbase16 @ 12963840   : int[NB*16]            -> 12,996,608
//   Pve     @ 12996608   : int[33]               -> 12,996,864
//   hist391 @ 12996864   : int[NB*NBKT]          -> 13,764,864
//   bbase391@ 13764864   : int[NB*NBKT]          -> 14,532,864
//   bstart  @ 14532864   : int[NBKT+1]           -> 14,534,912
//   dnstart @ 14534912   : int[NBKT*256+1]       -> 14,935,552
//   keyP    @ 14935552   : int[NEDGES]           -> 18,935,552
//   inv     @ 18935552   : int[PADCAP]           -> 22,939,648
//   srcS    @ 22939648   : int[PADCAP]           -> 26,943,744
//   msgE    @ 26943744   : ushort[PADCAP*64]     -> 155,074,816
#define OFF_FEATB    0ull
#define OFF_WT       12800000ull
#define OFF_HIST16   12931072ull
#define OFF_BBASE16  12963840ull
#define OFF_PVE      12996608ull
#define OFF_HIST391  12996864ull
#define OFF_BBASE391 13764864ull
#define OFF_BSTART   14532864ull
#define OFF_DNSTART  14534912ull
#define OFF_KEYP     14935552ull
#define OFF_INV      18935552ull
#define OFF_SRCS     22939648ull
#define OFF_MSGE     26943744ull
#define WS_NEED 155074816ull

using short8  = __attribute__((ext_vector_type(8))) short;
using floatx4 = __attribute__((ext_vector_type(4))) float;
using uintx4  = __attribute__((ext_vector_type(4))) unsigned int;

__device__ __forceinline__ unsigned short f2bf(float f) {
    union { float f; uint32_t u; } v; v.f = f;
    uint32_t u = v.u;
    return (unsigned short)((u + 0x7FFFu + ((u >> 16) & 1u)) >> 16);
}
__device__ __forceinline__ float bf2f(uint32_t u16) {
    union { uint32_t u; float f; } v; v.u = u16 << 16;
    return v.f;
}
__device__ __forceinline__ uint32_t pk2(float a, float b) {
    __hip_bfloat162 h = __float22bfloat162_rn(make_float2(a, b));
    union { __hip_bfloat162 h; uint32_t u; } v; v.h = h;
    return v.u;
}

// fused setup: feat->bf16, W->bf16 transposed, per-block rel hist + dst-bucket hist.
__global__ void k_setup(const float* __restrict__ feat, const float* __restrict__ W,
                        const int* __restrict__ et, const int* __restrict__ dst,
                        unsigned short* __restrict__ featB, unsigned short* __restrict__ Wt,
                        int* __restrict__ hist16, int* __restrict__ hist391) {
    __shared__ int cnt16[16];
    __shared__ int cnt391[NBKT];
    const int b = blockIdx.x;
    if (b < FEAT_BLKS) {
        int i = (b * 256 + threadIdx.x) * 4;
        const float4 f = *(const float4*)(feat + i);
        ushort4 o;
        o.x = f2bf(f.x); o.y = f2bf(f.y); o.z = f2bf(f.z); o.w = f2bf(f.w);
        *(ushort4*)(featB + i) = o;
    } else if (b < FEAT_BLKS + W_BLKS) {
        int t = (b - FEAT_BLKS) * 256 + threadIdx.x;   // 65536 total
        int r = t >> 12, n = (t >> 6) & 63, k = t & 63;
        Wt[t] = f2bf(W[(r << 12) + (k << 6) + n]);     // Wt[r][n][k] = W[r][k][n]
    } else {
        const int bb = b - (FEAT_BLKS + W_BLKS);
        if (threadIdx.x < 16) cnt16[threadIdx.x] = 0;
        for (int t = threadIdx.x; t < NBKT; t += 256) cnt391[t] = 0;
        __syncthreads();
        int start = bb * EPB;
        int end = min(NEDGES, start + EPB);
        for (int i = start + threadIdx.x; i < end; i += 256) {
            atomicAdd(&cnt16[et[i]], 1);
            atomicAdd(&cnt391[dst[i] >> 8], 1);
        }
        __syncthreads();
        if (threadIdx.x < 16) hist16[bb * 16 + threadIdx.x] = cnt16[threadIdx.x];
        for (int t = threadIdx.x; t < NBKT; t += 256)
            hist391[bb * NBKT + t] = cnt391[t];
    }
}

// merged: block 0 = relation scan (16 waves, with 64-pad via Pve); blocks 1.. = bucket scanA
__global__ void __launch_bounds__(1024)
k_scans(const int* __restrict__ hist16, int* __restrict__ bbase16,
        int* __restrict__ Pve,
        const int* __restrict__ hist391, int* __restrict__ bbase391,
        int* __restrict__ bstart) {
    int w = threadIdx.x >> 6;
    int lane = threadIdx.x & 63;
    if (blockIdx.x == 0) {
        __shared__ int s_cnt[16];
        __shared__ int s_P[17];
        int carry = 0;
        for (int c = 0; c < NB; c += 64) {
            int idx = c + lane;
            int v = (idx < NB) ? hist16[idx * 16 + w] : 0;
            int x = v;
            #pragma unroll
            for (int off = 1; off < 64; off <<= 1) {
                int y = __shfl_up(x, off);
                if (lane >= off) x += y;
            }
            if (idx < NB) bbase16[idx * 16 + w] = carry + x - v;
            carry += __shfl(x, 63);
        }
        if (lane == 0) s_cnt[w] = carry;
        __syncthreads();
        if (threadIdx.x == 0) {
            int p = 0;
            for (int r = 0; r < 16; ++r) {
                s_P[r] = p;
                Pve[r] = p;
                Pve[17 + r] = p + s_cnt[r];
                p += (s_cnt[r] + 63) & ~63;
            }
            s_P[16] = p;
            Pve[16] = p;
        }
        __syncthreads();
        int pw = s_P[w];
        for (int idx = lane; idx < NB; idx += 64)
            bbase16[idx * 16 + w] += pw;
    } else {
        int b = (blockIdx.x - 1) * 16 + w;
        if (b >= NBKT) return;
        int carry = 0;
        for (int c = 0; c < NB; c += 64) {
            int idx = c + lane;
            int v = (idx < NB) ? hist391[idx * NBKT + b] : 0;
            int x = v;
            #pragma unroll
            for (int off = 1; off < 64; off <<= 1) {
                int y = __shfl_up(x, off);
                if (lane >= off) x += y;
            }
            if (idx < NB) bbase391[idx * NBKT + b] = carry + x - v;
            carry += __shfl(x, 63);
        }
        if (lane == 0) bstart[b] = carry;   // totals; scanned in k_bscanB
    }
}

// bucket scan B: parallel exclusive scan over NBKT totals (one block, 512 thr)
__global__ void k_bscanB(int* __restrict__ bstart) {
    __shared__ int wtot[8];
    int t = threadIdx.x;
    int v = (t < NBKT) ? bstart[t] : 0;
    int lane = t & 63, w = t >> 6;
    int x = v;
    #pragma unroll
    for (int off = 1; off < 64; off <<= 1) {
        int y = __shfl_up(x, off);
        if (lane >= off) x += y;
    }
    if (lane == 63) wtot[w] = x;
    __syncthreads();
    int woff = 0;
    for (int i = 0; i < w; ++i) woff += wtot[i];
    if (t < NBKT) bstart[t] = woff + x - v;
    if (t == 511) {
        int total = 0;
        for (int i = 0; i < 8; ++i) total += wtot[i];
        bstart[NBKT] = total;
    }
}

// scatter: srcS[relpos] = src; keyP[bp] = (relpos<<8)|(dst&255)  (packed, one store).
__global__ void k_scatter(const int* __restrict__ et, const int* __restrict__ src,
                          const int* __restrict__ dst, const int* __restrict__ bbase16,
                          const int* __restrict__ bbase391, const int* __restrict__ bstart,
                          int* __restrict__ srcS, int* __restrict__ keyP) {
    __shared__ int base16[16];
    __shared__ int base391[NBKT];
    if (threadIdx.x < 16) base16[threadIdx.x] = bbase16[blockIdx.x * 16 + threadIdx.x];
    for (int t = threadIdx.x; t < NBKT; t += 256)
        base391[t] = bbase391[blockIdx.x * NBKT + t] + bstart[t];
    __syncthreads();
    int start = blockIdx.x * EPB;
    int end = min(NEDGES, start + EPB);
    for (int i = start + threadIdx.x; i < end; i += 256) {
        int r = et[i];
        int pos = atomicAdd(&base16[r], 1);
        srcS[pos] = src[i];
        int d = dst[i];
        int bp = atomicAdd(&base391[d >> 8], 1);
        keyP[bp] = (pos << 8) | (d & 255);   // pos < 2^20, fits
    }
}

// refine bucket order into full dst sort; write INVERSE map: inv[relpos] = dstpos.
__global__ void __launch_bounds__(256)
k_bsort(const int* __restrict__ keyP, const int* __restrict__ bstart,
        int* __restrict__ inv, int* __restrict__ dnstart) {
    __shared__ int cnt[256];
    __shared__ int nodebase[256];
    __shared__ int wtot[4];
    const int b = blockIdx.x;
    const int start = bstart[b], end = bstart[b + 1];
    const int t = threadIdx.x;
    cnt[t] = 0;
    __syncthreads();
    for (int e = start + t; e < end; e += 256)
        atomicAdd(&cnt[keyP[e] & 255], 1);
    __syncthreads();
    int v = cnt[t];
    int lane = t & 63, w = t >> 6;
    int x = v;
    #pragma unroll
    for (int off = 1; off < 64; off <<= 1) {
        int y = __shfl_up(x, off);
        if (lane >= off) x += y;
    }
    if (lane == 63) wtot[w] = x;
    __syncthreads();
    int woff = 0;
    for (int i = 0; i < w; ++i) woff += wtot[i];
    nodebase[t] = woff + x - v;          // exclusive scan
    cnt[t] = 0;
    __syncthreads();
    dnstart[b * 256 + t] = start + nodebase[t];
    if (b == NBKT - 1 && t == 255) dnstart[NBKT * 256] = end;
    for (int e = start + t; e < end; e += 256) {
        int k = keyP[e];
        int node = k & 255;
        int rk = atomicAdd(&cnt[node], 1);
        inv[k >> 8] = start + nodebase[node] + rk;   // relpos -> dstpos
    }
}

// Phase A: per 64-edge tile (single relation), GEMM -> scatter row to its
// DST-SORTED position (inv map).  R11 structure (best measured), with the 8
// feature gathers as VOLATILE inline-asm loads (unsinkable; compiler-hint
// pinning failed twice: VGPR 52 w/ sched_barrier, 44 w/ keep-alive asm) +
// one s_waitcnt vmcnt(0) + sched_barrier(0) (rule #18 ordering).
__global__ void __launch_bounds__(256)
k_computeA(const unsigned short* __restrict__ featB,
           const unsigned short* __restrict__ Wt,
           const int* __restrict__ srcS, const int* __restrict__ Pve,
           const int* __restrict__ inv,
           unsigned short* __restrict__ msgE) {
    __shared__ float lds[4][16 * 68];   // per-wave 16x64 transpose, stride 68
    const int w = threadIdx.x >> 6;
    const int t = blockIdx.x * 4 + w;
    const int base = t * 64;
    const int lane = threadIdx.x & 63;

    // wave-parallel relation lookup (base is wave-uniform)
    int pv = (lane < 33) ? Pve[lane] : 0x7fffffff;
    int total = __shfl(pv, 16);
    if (base >= total) return;
    unsigned long long bm = __ballot(lane >= 1 && lane <= 16 && pv <= base);
    int r = __popcll(bm);                 // Pve[r] <= base < Pve[r+1]
    int validEnd = __shfl(pv, 17 + r);

    const int quad = lane >> 4;
    const int l16 = lane & 15;
    const int rr = lane >> 2, seg = lane & 3;

    // --- load cluster: srcS ---
    int s[4];
    #pragma unroll
    for (int tm = 0; tm < 4; ++tm) {
        int row = base + tm * 16 + l16;
        s[tm] = (row < validEnd) ? srcS[row] : 0;
    }
    // --- load cluster: output positions ---
    int dpos[4]; bool vld[4];
    #pragma unroll
    for (int tm = 0; tm < 4; ++tm) {
        int g = base + tm * 16 + rr;
        vld[tm] = (g < validEnd);
        dpos[tm] = vld[tm] ? inv[g] : 0;
    }
    // --- load cluster: W fragments (L2-hot) ---
    const unsigned short* wr = Wt + (r << 12);
    short8 bfr[4][2];
    #pragma unroll
    for (int tn = 0; tn < 4; ++tn)
        #pragma unroll
        for (int ks = 0; ks < 2; ++ks)
            bfr[tn][ks] = *(const short8*)(wr + ((tn * 16 + l16) << 6) + ks * 32 + quad * 8);
    // --- all 8 feature gathers: volatile asm loads, UNSINKABLE ---
    short8 a[4][2];
    #pragma unroll
    for (int tm = 0; tm < 4; ++tm) {
        const unsigned short* fp = featB + ((size_t)s[tm] << 6) + quad * 8;
        asm volatile("global_load_dwordx4 %0, %1, off"
                     : "=&v"(a[tm][0]) : "v"(fp) : "memory");
        asm volatile("global_load_dwordx4 %0, %1, off offset:64"
                     : "=&v"(a[tm][1]) : "v"(fp) : "memory");
    }
    // one drain for the whole cluster; sched_barrier keeps MFMAs below it
    asm volatile("s_waitcnt vmcnt(0)" ::: "memory");
    __builtin_amdgcn_sched_barrier(0);

    // --- compute + scatter (R11 pattern: LDS transpose, rr/seg 16-B stores) ---
    #pragma unroll
    for (int tm = 0; tm < 4; ++tm) {
        #pragma unroll
        for (int tn = 0; tn < 4; ++tn) {
            floatx4 c = {0.f, 0.f, 0.f, 0.f};
            c = __builtin_amdgcn_mfma_f32_16x16x32_bf16(a[tm][0], bfr[tn][0], c, 0, 0, 0);
            c = __builtin_amdgcn_mfma_f32_16x16x32_bf16(a[tm][1], bfr[tn][1], c, 0, 0, 0);
            #pragma unroll
            for (int j = 0; j < 4; ++j)
                lds[w][(quad * 4 + j) * 68 + tn * 16 + l16] = c[j];
        }
        // lane group (rr,seg) emits output row rr at its dst-sorted position
        if (vld[tm]) {
            const float* lp = &lds[w][rr * 68 + seg * 16];
            uintx4 o0, o1;
            o0.x = pk2(lp[0],  lp[1]);  o0.y = pk2(lp[2],  lp[3]);
            o0.z = pk2(lp[4],  lp[5]);  o0.w = pk2(lp[6],  lp[7]);
            o1.x = pk2(lp[8],  lp[9]);  o1.y = pk2(lp[10], lp[11]);
            o1.z = pk2(lp[12], lp[13]); o1.w = pk2(lp[14], lp[15]);
            uintx4* op = (uintx4*)(msgE + (size_t)dpos[tm] * 64 + seg * 16);
            op[0] = o0;
            op[1] = o1;
        }
    }
}

// Phase B: one wave per dst node; rows CONTIGUOUS in msgE -> sequential reads.
__global__ void __launch_bounds__(256)
k_reduce(const unsigned short* __restrict__ msgE,
         const int* __restrict__ dnstart, float* __restrict__ out) {
    int n = blockIdx.x * 4 + (threadIdx.x >> 6);
    if (n >= NDN) return;
    int lane = threadIdx.x & 63;
    int start = dnstart[n];
    int end = dnstart[n + 1];
    int c8 = (lane & 7) * 8;   // ushort col offset
    float a0 = 0.f, a1 = 0.f, a2 = 0.f, a3 = 0.f;
    float a4 = 0.f, a5 = 0.f, a6 = 0.f, a7 = 0.f;
    int row = start + (lane >> 3);
    for (; row + 8 < end; row += 16) {
        uintx4 v0 = *(const uintx4*)(msgE + (size_t)row * 64 + c8);
        uintx4 v1 = *(const uintx4*)(msgE + (size_t)(row + 8) * 64 + c8);
        a0 += bf2f(v0.x & 0xffffu); a1 += bf2f(v0.x >> 16);
        a2 += bf2f(v0.y & 0xffffu); a3 += bf2f(v0.y >> 16);
        a4 += bf2f(v0.z & 0xffffu); a5 += bf2f(v0.z >> 16);
        a6 += bf2f(v0.w & 0xffffu); a7 += bf2f(v0.w >> 16);
        a0 += bf2f(v1.x & 0xffffu); a1 += bf2f(v1.x >> 16);
        a2 += bf2f(v1.y & 0xffffu); a3 += bf2f(v1.y >> 16);
        a4 += bf2f(v1.z & 0xffffu); a5 += bf2f(v1.z >> 16);
        a6 += bf2f(v1.w & 0xffffu); a7 += bf2f(v1.w >> 16);
    }
    if (row < end) {
        uintx4 v = *(const uintx4*)(msgE + (size_t)row * 64 + c8);
        a0 += bf2f(v.x & 0xffffu); a1 += bf2f(v.x >> 16);
        a2 += bf2f(v.y & 0xffffu); a3 += bf2f(v.y >> 16);
        a4 += bf2f(v.z & 0xffffu); a5 += bf2f(v.z >> 16);
        a6 += bf2f(v.w & 0xffffu); a7 += bf2f(v.w >> 16);
    }
    #pragma unroll
    for (int m = 8; m <= 32; m <<= 1) {
        a0 += __shfl_xor(a0, m); a1 += __shfl_xor(a1, m);
        a2 += __shfl_xor(a2, m); a3 += __shfl_xor(a3, m);
        a4 += __shfl_xor(a4, m); a5 += __shfl_xor(a5, m);
        a6 += __shfl_xor(a6, m); a7 += __shfl_xor(a7, m);
    }
    if (lane < 8) {
        float* op = out + (size_t)n * 64 + lane * 8;
        *(float4*)(op)     = make_float4(a0, a1, a2, a3);
        *(float4*)(op + 4) = make_float4(a4, a5, a6, a7);
    }
}

// Fallback (ws too small): correctness-only per-edge kernel on raw fp32 inputs.
__global__ void __launch_bounds__(256)
k_fb(const float* __restrict__ feat, const float* __restrict__ W,
     const int* __restrict__ src, const int* __restrict__ dst,
     const int* __restrict__ et, float* __restrict__ out) {
    int e = blockIdx.x * 4 + (threadIdx.x >> 6);
    if (e >= NEDGES) return;
    int c = threadIdx.x & 63;
    int s = src[e], d = dst[e], r = et[e];
    const float* fr = feat + (size_t)s * 64;
    const float* wr = W + ((size_t)r << 12);
    float acc = 0.f;
    for (int k = 0; k < 64; ++k) acc += fr[k] * wr[k * 64 + c];
    atomicAdd(out + (size_t)d * 64 + c, acc);
}

extern "C" void kernel_launch(void* const* d_in, const int* in_sizes, int n_in,
                              void* d_out, int out_size, void* d_ws, size_t ws_size,
                              hipStream_t stream) {
    const float* feat = (const float*)d_in[0];
    const float* W    = (const float*)d_in[1];
    const int* src    = (const int*)d_in[2];
    const int* dst    = (const int*)d_in[3];
    const int* et     = (const int*)d_in[4];
    float* out = (float*)d_out;
    char* ws = (char*)d_ws;

    unsigned short* featB = (unsigned short*)(ws + OFF_FEATB);
    unsigned short* Wt    = (unsigned short*)(ws + OFF_WT);
    int* hist16   = (int*)(ws + OFF_HIST16);
    int* bbase16  = (int*)(ws + OFF_BBASE16);
    int* Pve      = (int*)(ws + OFF_PVE);
    int* hist391  = (int*)(ws + OFF_HIST391);
    int* bbase391 = (int*)(ws + OFF_BBASE391);
    int* bstart   = (int*)(ws + OFF_BSTART);
    int* dnstart  = (int*)(ws + OFF_DNSTART);
    int* keyP     = (int*)(ws + OFF_KEYP);
    int* inv      = (int*)(ws + OFF_INV);
    int* srcS     = (int*)(ws + OFF_SRCS);
    unsigned short* msgE = (unsigned short*)(ws + OFF_MSGE);

    if (ws_size >= WS_NEED) {
        k_setup<<<SETUP_BLKS, 256, 0, stream>>>(feat, W, et, dst, featB, Wt,
                                                hist16, hist391);
        k_scans<<<SCANS_BLKS, 1024, 0, stream>>>(hist16, bbase16, Pve, hist391,
                                                 bbase391, bstart);
        k_bscanB<<<1, 512, 0, stream>>>(bstart);
        k_scatter<<<NB, 256, 0, stream>>>(et, src, dst, bbase16, bbase391, bstart,
                                          srcS, keyP);
        k_bsort<<<NBKT, 256, 0, stream>>>(keyP, bstart, inv, dnstart);
        k_computeA<<<(MAXTILES + 3) / 4, 256, 0, stream>>>(featB, Wt, srcS, Pve,
                                                           inv, msgE);
        k_reduce<<<(NDN + 3) / 4, 256, 0, stream>>>(msgE, dnstart, out);
    } else {
        hipMemsetAsync(d_out, 0, (size_t)out_size * sizeof(float), stream);
        k_fb<<<(NEDGES + 3) / 4, 256, 0, stream>>>(feat, W, src, dst, et, out);
    }
}